// Round 5
// baseline (101.560 us; speedup 1.0000x reference)
//
#include <hip/hip_runtime.h>
#include <hip/hip_fp16.h>
#include <math.h>

#define N_  2
#define C_  128
#define H_  128
#define W_  128
#define G_  4
#define GC_ 32
#define P_  9
#define WT  16      // pixels per block (along w)
#define X1S 132     // x1/out tile stride (floats)
#define OFS 73      // offs stride (floats)

#define DESC_BYTES ((size_t)N_ * H_ * W_ * G_ * P_ * 16)   // 18.9 MB

union HU { __half h; unsigned short u; };
static __device__ __forceinline__ unsigned int f2h(float f) {
    HU x; x.h = __float2half(f); return (unsigned int)x.u;
}
static __device__ __forceinline__ float h2f(unsigned int v) {
    HU x; x.u = (unsigned short)v; return __half2float(x.h);
}

// ===================== K1: dw-conv -> LN -> GELU -> offset linear -> descriptors =====================
// LDS: x1 16*132*4 = 8448 ; offs 16*73*4 = 4672 at 8448 (red1/red2 alias offs region)
#define K1_ARENA (8448 + 4672)

__global__ __launch_bounds__(256, 6)
void dcn_stage1(const float* __restrict__ inp,   // [N,C,H,W]
                const float* __restrict__ dww,   // [3,3,1,C]
                const float* __restrict__ dwb,   // [C]
                const float* __restrict__ lng,   // [C]
                const float* __restrict__ lnb,   // [C]
                const float* __restrict__ offw,  // [72,C]
                const float* __restrict__ offb,  // [72]
                uint4* __restrict__ desc)        // [N*H*W, 36]
{
    __shared__ __align__(16) char arena[K1_ARENA];
    float* x1   = (float*)arena;                 // 16 x 132
    float* offs = (float*)(arena + 8448);        // 16 x 73
    float* red1 = (float*)(arena + 8448);        // 16x16 (A2 only, alias)
    float* red2 = (float*)(arena + 9472);

    const int t   = threadIdx.x;
    const int bid = blockIdx.x;
    const int sw  = ((bid & 7) << 8) | (bid >> 3);   // XCD swizzle (2048 = 8*256)
    const int wt  = sw & 7;
    const int h   = (sw >> 3) & (H_ - 1);
    const int n   = sw >> 10;
    const int w0  = wt * WT;
    const int pixbase = (n * H_ + h) * W_ + w0;

    // ---------- A1: depthwise 3x3 conv (+bias), vectorized ----------
    // thread = (pixel-quad jq, channel-pair q). Loads: 9 float2 weights + 18 float4 input.
    {
        const int jq = t & 3;
        const int q  = t >> 2;
        const int c0 = 2 * q;
        float wg0[9], wg1[9];
        #pragma unroll
        for (int k = 0; k < 9; ++k) {
            const float2 wk = *(const float2*)&dww[k * C_ + c0];
            wg0[k] = wk.x; wg1[k] = wk.y;
        }
        const float2 bb = *(const float2*)&dwb[c0];
        const int bcol = w0 + 4 * jq - 4;            // aligned float4 base col
        float a0[4] = {bb.x, bb.x, bb.x, bb.x};
        float a1[4] = {bb.y, bb.y, bb.y, bb.y};
        const float4 z4 = make_float4(0.f, 0.f, 0.f, 0.f);
        #pragma unroll
        for (int r = 0; r < 3; ++r) {
            const int hr = h - 1 + r;
            const bool rv = (hr >= 0) && (hr < H_);
            #pragma unroll
            for (int ch = 0; ch < 2; ++ch) {
                const float* row = inp + (((size_t)n * C_ + (c0 + ch)) * H_ + hr) * W_;
                // window cols [bcol+3, bcol+8] = [wabs-1, wabs+4]; edge float4s zero-filled
                const float4 A = (rv && bcol >= 0)   ? *(const float4*)&row[bcol]     : z4;
                const float4 B = rv                  ? *(const float4*)&row[bcol + 4] : z4;
                const float4 Cc= (rv && bcol <= 116) ? *(const float4*)&row[bcol + 8] : z4;
                const float wv0 = A.w, wv1 = B.x, wv2 = B.y, wv3 = B.z, wv4 = B.w, wv5 = Cc.x;
                const float* wg = ch ? wg1 : wg0;
                float* acc = ch ? a1 : a0;
                acc[0] = fmaf(wv0, wg[r*3+0], acc[0]);
                acc[0] = fmaf(wv1, wg[r*3+1], acc[0]);
                acc[0] = fmaf(wv2, wg[r*3+2], acc[0]);
                acc[1] = fmaf(wv1, wg[r*3+0], acc[1]);
                acc[1] = fmaf(wv2, wg[r*3+1], acc[1]);
                acc[1] = fmaf(wv3, wg[r*3+2], acc[1]);
                acc[2] = fmaf(wv2, wg[r*3+0], acc[2]);
                acc[2] = fmaf(wv3, wg[r*3+1], acc[2]);
                acc[2] = fmaf(wv4, wg[r*3+2], acc[2]);
                acc[3] = fmaf(wv3, wg[r*3+0], acc[3]);
                acc[3] = fmaf(wv4, wg[r*3+1], acc[3]);
                acc[3] = fmaf(wv5, wg[r*3+2], acc[3]);
            }
        }
        #pragma unroll
        for (int jj = 0; jj < 4; ++jj)
            *(float2*)&x1[(4 * jq + jj) * X1S + c0] = make_float2(a0[jj], a1[jj]);
    }
    __syncthreads();

    // ---------- A2a: LN partial stats ----------
    {
        const int w  = t & 15;
        const int q8 = t >> 4;
        const float4 xa = *(const float4*)&x1[w * X1S + q8 * 8];
        const float4 xb = *(const float4*)&x1[w * X1S + q8 * 8 + 4];
        const float s1 = xa.x + xa.y + xa.z + xa.w + xb.x + xb.y + xb.z + xb.w;
        float s2 = xa.x * xa.x;
        s2 = fmaf(xa.y, xa.y, s2); s2 = fmaf(xa.z, xa.z, s2); s2 = fmaf(xa.w, xa.w, s2);
        s2 = fmaf(xb.x, xb.x, s2); s2 = fmaf(xb.y, xb.y, s2);
        s2 = fmaf(xb.z, xb.z, s2); s2 = fmaf(xb.w, xb.w, s2);
        red1[q8 * 16 + w] = s1;
        red2[q8 * 16 + w] = s2;
        __syncthreads();

        // ---------- A2b: finish LN + exact GELU ----------
        float t1 = 0.f, t2 = 0.f;
        #pragma unroll
        for (int j = 0; j < 16; ++j) { t1 += red1[j * 16 + w]; t2 += red2[j * 16 + w]; }
        const float mean = t1 * (1.f / 128.f);
        const float var  = t2 * (1.f / 128.f) - mean * mean;
        const float rstd = rsqrtf(var + 1e-6f);
        float v[8] = {xa.x, xa.y, xa.z, xa.w, xb.x, xb.y, xb.z, xb.w};
        #pragma unroll
        for (int i = 0; i < 8; ++i) {
            const int c = q8 * 8 + i;
            float y = (v[i] - mean) * rstd * lng[c] + lnb[c];
            v[i] = 0.5f * y * (1.f + erff(y * 0.70710678118654752440f));
        }
        *(float4*)&x1[w * X1S + q8 * 8]     = make_float4(v[0], v[1], v[2], v[3]);
        *(float4*)&x1[w * X1S + q8 * 8 + 4] = make_float4(v[4], v[5], v[6], v[7]);
    }
    __syncthreads();

    // ---------- A3: offset linear ----------
    {
        const int pix  = t & 15;
        const int s    = t >> 4;
        const bool has5 = (s < 8);
        float acc[5];
        #pragma unroll
        for (int j = 0; j < 4; ++j) acc[j] = offb[s * 4 + j];
        acc[4] = has5 ? offb[64 + s] : 0.f;
        #pragma unroll 2
        for (int cb = 0; cb < C_; cb += 8) {
            const float4 xa = *(const float4*)&x1[pix * X1S + cb];
            const float4 xb = *(const float4*)&x1[pix * X1S + cb + 4];
            #pragma unroll
            for (int j = 0; j < 4; ++j) {
                const int o = s * 4 + j;
                const float4 wa = *(const float4*)&offw[o * C_ + cb];
                const float4 wb = *(const float4*)&offw[o * C_ + cb + 4];
                acc[j] = fmaf(xa.x, wa.x, acc[j]);
                acc[j] = fmaf(xa.y, wa.y, acc[j]);
                acc[j] = fmaf(xa.z, wa.z, acc[j]);
                acc[j] = fmaf(xa.w, wa.w, acc[j]);
                acc[j] = fmaf(xb.x, wb.x, acc[j]);
                acc[j] = fmaf(xb.y, wb.y, acc[j]);
                acc[j] = fmaf(xb.z, wb.z, acc[j]);
                acc[j] = fmaf(xb.w, wb.w, acc[j]);
            }
            if (has5) {
                const int o = 64 + s;
                const float4 wa = *(const float4*)&offw[o * C_ + cb];
                const float4 wb = *(const float4*)&offw[o * C_ + cb + 4];
                acc[4] = fmaf(xa.x, wa.x, acc[4]);
                acc[4] = fmaf(xa.y, wa.y, acc[4]);
                acc[4] = fmaf(xa.z, wa.z, acc[4]);
                acc[4] = fmaf(xa.w, wa.w, acc[4]);
                acc[4] = fmaf(xb.x, wb.x, acc[4]);
                acc[4] = fmaf(xb.y, wb.y, acc[4]);
                acc[4] = fmaf(xb.z, wb.z, acc[4]);
                acc[4] = fmaf(xb.w, wb.w, acc[4]);
            }
        }
        #pragma unroll
        for (int j = 0; j < 4; ++j) offs[pix * OFS + s * 4 + j] = acc[j];
        if (has5) offs[pix * OFS + 64 + s] = acc[4];
    }
    __syncthreads();

    // ---------- A4: pack per-tap descriptor -> global (coalesced 16B stream) ----------
    {
        for (int tap = t; tap < WT * G_ * P_; tap += 256) {
            const int pg  = tap / 9;
            const int p   = tap - pg * 9;
            const int pix = pg >> 2;
            const int g   = pg & 3;
            const float ox = offs[pix * OFS + g * 18 + 2 * p];
            const float oy = offs[pix * OFS + g * 18 + 2 * p + 1];
            const float fy = (float)(h + (p % 3)) + oy;
            const float fx = (float)(w0 + pix + (p / 3)) + ox;
            const float y0f = floorf(fy);
            const float x0f = floorf(fx);
            const float wy = fy - y0f;
            const float wx = fx - x0f;
            const int y0 = (int)y0f;
            const int x0 = (int)x0f;
            const int yc0 = min(max(y0, 1), H_) - 1;
            const int yc1 = min(max(y0 + 1, 1), H_) - 1;
            const int xc0 = min(max(x0, 1), W_) - 1;
            const int xc1 = min(max(x0 + 1, 1), W_) - 1;
            const float a0 = (1.f - wy) * ((y0 >= 1 && y0 <= H_) ? 1.f : 0.f);
            const float a1 = wy * ((y0 + 1 >= 1 && y0 + 1 <= H_) ? 1.f : 0.f);
            const float b0 = (1.f - wx) * ((x0 >= 1 && x0 <= W_) ? 1.f : 0.f);
            const float b1 = wx * ((x0 + 1 >= 1 && x0 + 1 <= W_) ? 1.f : 0.f);
            const unsigned int i00 = (unsigned int)(yc0 * W_ + xc0);
            const unsigned int i01 = (unsigned int)(yc0 * W_ + xc1);
            const unsigned int i10 = (unsigned int)(yc1 * W_ + xc0);
            const unsigned int i11 = (unsigned int)(yc1 * W_ + xc1);
            desc[(size_t)pixbase * 36 + tap] =
                make_uint4(i00 | (i01 << 16),
                           i10 | (i11 << 16),
                           f2h(a0 * b0) | (f2h(a0 * b1) << 16),
                           f2h(a1 * b0) | (f2h(a1 * b1) << 16));
        }
    }
}

// ===================== K2: pure gather (no inter-phase barriers, deep ILP) =====================
__global__ __launch_bounds__(512, 4)
void dcn_gather(const float* __restrict__ xin,   // [N,H,W,C]
                const uint4* __restrict__ desc,  // [N*H*W, 36]
                float* __restrict__ out)         // [N,C,H,W]
{
    __shared__ __align__(16) float stage[WT * X1S];   // 16 x 132

    const int t   = threadIdx.x;
    const int bid = blockIdx.x;
    const int sw  = ((bid & 7) << 8) | (bid >> 3);    // same XCD swizzle as K1
    const int wt  = sw & 7;
    const int h   = (sw >> 3) & (H_ - 1);
    const int n   = sw >> 10;
    const int w0  = wt * WT;
    const int pixbase = (n * H_ + h) * W_ + w0;

    {
        const int k   = t & 7;        // channel quad within group
        const int pl  = t >> 3;       // 0..63 = pix*4+g
        const int pix = pl >> 2;
        const int g   = pl & 3;
        const uint4* dp = desc + (size_t)(pixbase + pix) * 36 + g * 9;
        const float4* xg = (const float4*)xin + (size_t)n * (H_ * W_ * (C_ / 4)) + g * (GC_ / 4) + k;

        uint4 d[9];
        #pragma unroll
        for (int p = 0; p < P_; ++p) d[p] = dp[p];

        float4 acc = make_float4(0.f, 0.f, 0.f, 0.f);
        #pragma unroll
        for (int p = 0; p < P_; ++p) {
            const float4 v00 = xg[(d[p].x & 0xFFFFu) * 32u];
            const float4 v01 = xg[(d[p].x >> 16) * 32u];
            const float4 v10 = xg[(d[p].y & 0xFFFFu) * 32u];
            const float4 v11 = xg[(d[p].y >> 16) * 32u];
            const float w00 = h2f(d[p].z & 0xFFFFu), w01 = h2f(d[p].z >> 16);
            const float w10 = h2f(d[p].w & 0xFFFFu), w11 = h2f(d[p].w >> 16);
            acc.x = fmaf(w00, v00.x, acc.x);
            acc.y = fmaf(w00, v00.y, acc.y);
            acc.z = fmaf(w00, v00.z, acc.z);
            acc.w = fmaf(w00, v00.w, acc.w);
            acc.x = fmaf(w01, v01.x, acc.x);
            acc.y = fmaf(w01, v01.y, acc.y);
            acc.z = fmaf(w01, v01.z, acc.z);
            acc.w = fmaf(w01, v01.w, acc.w);
            acc.x = fmaf(w10, v10.x, acc.x);
            acc.y = fmaf(w10, v10.y, acc.y);
            acc.z = fmaf(w10, v10.z, acc.z);
            acc.w = fmaf(w10, v10.w, acc.w);
            acc.x = fmaf(w11, v11.x, acc.x);
            acc.y = fmaf(w11, v11.y, acc.y);
            acc.z = fmaf(w11, v11.z, acc.z);
            acc.w = fmaf(w11, v11.w, acc.w);
        }
        *(float4*)&stage[pix * X1S + g * GC_ + k * 4] = acc;
    }
    __syncthreads();

    // transpose write: NCHW, 64B segments per c-plane
    {
        const int pix = t & 15;
        const int c0  = t >> 4;       // 0..31
        #pragma unroll
        for (int i = 0; i < 4; ++i) {
            const int c = c0 + 32 * i;
            out[(((size_t)n * C_ + c) * H_ + h) * W_ + w0 + pix] = stage[pix * X1S + c];
        }
    }
}

// ===================== fallback: monolithic (R3) if ws too small =====================
#define ARENA_BYTES 22336
__global__ __launch_bounds__(256, 6)
void dcn_fused_mono(const float* __restrict__ inp, const float* __restrict__ xin,
                    const float* __restrict__ dww, const float* __restrict__ dwb,
                    const float* __restrict__ lng, const float* __restrict__ lnb,
                    const float* __restrict__ offw, const float* __restrict__ offb,
                    float* __restrict__ out)
{
    __shared__ __align__(16) char arena[ARENA_BYTES];
    float*  x1     = (float*)arena;
    uint4*  desc4  = (uint4*)(arena + 8448);
    float*  red1   = (float*)(arena + 8448);
    float*  red2   = (float*)(arena + 9472);
    float*  offs   = (float*)(arena + 17664);

    const int t   = threadIdx.x;
    const int bid = blockIdx.x;
    const int sw  = ((bid & 7) << 8) | (bid >> 3);
    const int wt  = sw & 7;
    const int h   = (sw >> 3) & (H_ - 1);
    const int n   = sw >> 10;
    const int w0  = wt * WT;

    {
        const int w = t & 15;
        const int q = t >> 4;
        float s1 = 0.f, s2 = 0.f;
        const int wcb = w0 + w - 1;
        #pragma unroll
        for (int i = 0; i < 8; ++i) {
            const int c = q * 8 + i;
            float acc = dwb[c];
            #pragma unroll
            for (int r = 0; r < 3; ++r) {
                const int hr = h - 1 + r;
                const bool rv = (hr >= 0) && (hr < H_);
                const float* row = inp + (((size_t)n * C_ + c) * H_ + hr) * W_;
                #pragma unroll
                for (int s = 0; s < 3; ++s) {
                    const int wc = wcb + s;
                    const float v = (rv && wc >= 0 && wc < W_) ? row[wc] : 0.f;
                    acc = fmaf(v, dww[(r * 3 + s) * C_ + c], acc);
                }
            }
            x1[w * X1S + c] = acc;
            s1 += acc;
            s2 = fmaf(acc, acc, s2);
        }
        red1[q * 16 + w] = s1;
        red2[q * 16 + w] = s2;
    }
    __syncthreads();
    {
        const int w = t & 15;
        const int q = t >> 4;
        float s1 = 0.f, s2 = 0.f;
        #pragma unroll
        for (int j = 0; j < 16; ++j) { s1 += red1[j * 16 + w]; s2 += red2[j * 16 + w]; }
        const float mean = s1 * (1.f / 128.f);
        const float var  = s2 * (1.f / 128.f) - mean * mean;
        const float rstd = rsqrtf(var + 1e-6f);
        #pragma unroll
        for (int i = 0; i < 8; ++i) {
            const int c = q * 8 + i;
            float v = x1[w * X1S + c];
            v = (v - mean) * rstd * lng[c] + lnb[c];
            v = 0.5f * v * (1.f + erff(v * 0.70710678118654752440f));
            x1[w * X1S + c] = v;
        }
    }
    __syncthreads();
    {
        const int pix  = t & 15;
        const int s    = t >> 4;
        const bool has5 = (s < 8);
        float acc[5];
        #pragma unroll
        for (int j = 0; j < 4; ++j) acc[j] = offb[s * 4 + j];
        acc[4] = has5 ? offb[64 + s] : 0.f;
        #pragma unroll 2
        for (int cb = 0; cb < C_; cb += 8) {
            const float4 xa = *(const float4*)&x1[pix * X1S + cb];
            const float4 xb = *(const float4*)&x1[pix * X1S + cb + 4];
            #pragma unroll
            for (int j = 0; j < 4; ++j) {
                const int o = s * 4 + j;
                const float4 wa = *(const float4*)&offw[o * C_ + cb];
                const float4 wb = *(const float4*)&offw[o * C_ + cb + 4];
                acc[j] = fmaf(xa.x, wa.x, acc[j]);
                acc[j] = fmaf(xa.y, wa.y, acc[j]);
                acc[j] = fmaf(xa.z, wa.z, acc[j]);
                acc[j] = fmaf(xa.w, wa.w, acc[j]);
                acc[j] = fmaf(xb.x, wb.x, acc[j]);
                acc[j] = fmaf(xb.y, wb.y, acc[j]);
                acc[j] = fmaf(xb.z, wb.z, acc[j]);
                acc[j] = fmaf(xb.w, wb.w, acc[j]);
            }
            if (has5) {
                const int o = 64 + s;
                const float4 wa = *(const float4*)&offw[o * C_ + cb];
                const float4 wb = *(const float4*)&offw[o * C_ + cb + 4];
                acc[4] = fmaf(xa.x, wa.x, acc[4]);
                acc[4] = fmaf(xa.y, wa.y, acc[4]);
                acc[4] = fmaf(xa.z, wa.z, acc[4]);
                acc[4] = fmaf(xa.w, wa.w, acc[4]);
                acc[4] = fmaf(xb.x, wb.x, acc[4]);
                acc[4] = fmaf(xb.y, wb.y, acc[4]);
                acc[4] = fmaf(xb.z, wb.z, acc[4]);
                acc[4] = fmaf(xb.w, wb.w, acc[4]);
            }
        }
        #pragma unroll
        for (int j = 0; j < 4; ++j) offs[pix * OFS + s * 4 + j] = acc[j];
        if (has5) offs[pix * OFS + 64 + s] = acc[4];
    }
    __syncthreads();
    {
        for (int tap = t; tap < WT * G_ * P_; tap += 256) {
            const int pg  = tap / 9;
            const int p   = tap - pg * 9;
            const int pix = pg >> 2;
            const int g   = pg & 3;
            const float ox = offs[pix * OFS + g * 18 + 2 * p];
            const float oy = offs[pix * OFS + g * 18 + 2 * p + 1];
            const float fy = (float)(h + (p % 3)) + oy;
            const float fx = (float)(w0 + pix + (p / 3)) + ox;
            const float y0f = floorf(fy);
            const float x0f = floorf(fx);
            const float wy = fy - y0f;
            const float wx = fx - x0f;
            const int y0 = (int)y0f;
            const int x0 = (int)x0f;
            const int yc0 = min(max(y0, 1), H_) - 1;
            const int yc1 = min(max(y0 + 1, 1), H_) - 1;
            const int xc0 = min(max(x0, 1), W_) - 1;
            const int xc1 = min(max(x0 + 1, 1), W_) - 1;
            const float a0 = (1.f - wy) * ((y0 >= 1 && y0 <= H_) ? 1.f : 0.f);
            const float a1 = wy * ((y0 + 1 >= 1 && y0 + 1 <= H_) ? 1.f : 0.f);
            const float b0 = (1.f - wx) * ((x0 >= 1 && x0 <= W_) ? 1.f : 0.f);
            const float b1 = wx * ((x0 + 1 >= 1 && x0 + 1 <= W_) ? 1.f : 0.f);
            const unsigned int i00 = (unsigned int)(yc0 * W_ + xc0);
            const unsigned int i01 = (unsigned int)(yc0 * W_ + xc1);
            const unsigned int i10 = (unsigned int)(yc1 * W_ + xc0);
            const unsigned int i11 = (unsigned int)(yc1 * W_ + xc1);
            desc4[tap] = make_uint4(i00 | (i01 << 16),
                                    i10 | (i11 << 16),
                                    f2h(a0 * b0) | (f2h(a0 * b1) << 16),
                                    f2h(a1 * b0) | (f2h(a1 * b1) << 16));
        }
    }
    __syncthreads();
    {
        const int k    = t & 15;
        const int slot = t >> 4;
        const float2* xb2 = (const float2*)xin + (size_t)n * (H_ * W_ * C_ / 2) + k;
        float2* st = (float2*)x1;
        #pragma unroll 1
        for (int it = 0; it < 2; ++it) {
            const int pairA = it * 32 + slot;
            const int pairB = pairA + 16;
            const int pixA = pairA >> 2, gA = pairA & 3;
            const int pixB = pairB >> 2, gB = pairB & 3;
            const float2* xgA = xb2 + gA * (GC_ / 2);
            const float2* xgB = xb2 + gB * (GC_ / 2);
            const uint4* dAp = desc4 + pairA * 9;
            const uint4* dBp = desc4 + pairB * 9;
            float aAx = 0.f, aAy = 0.f, aBx = 0.f, aBy = 0.f;
            #pragma unroll
            for (int p = 0; p < P_; ++p) {
                const uint4 da = dAp[p];
                const uint4 db = dBp[p];
                const float2 vA00 = xgA[(da.x & 0xFFFFu) * 64u];
                const float2 vA01 = xgA[(da.x >> 16) * 64u];
                const float2 vA10 = xgA[(da.y & 0xFFFFu) * 64u];
                const float2 vA11 = xgA[(da.y >> 16) * 64u];
                const float2 vB00 = xgB[(db.x & 0xFFFFu) * 64u];
                const float2 vB01 = xgB[(db.x >> 16) * 64u];
                const float2 vB10 = xgB[(db.y & 0xFFFFu) * 64u];
                const float2 vB11 = xgB[(db.y >> 16) * 64u];
                const float wA00 = h2f(da.z & 0xFFFFu), wA01 = h2f(da.z >> 16);
                const float wA10 = h2f(da.w & 0xFFFFu), wA11 = h2f(da.w >> 16);
                const float wB00 = h2f(db.z & 0xFFFFu), wB01 = h2f(db.z >> 16);
                const float wB10 = h2f(db.w & 0xFFFFu), wB11 = h2f(db.w >> 16);
                aAx = fmaf(wA00, vA00.x, aAx); aAy = fmaf(wA00, vA00.y, aAy);
                aAx = fmaf(wA01, vA01.x, aAx); aAy = fmaf(wA01, vA01.y, aAy);
                aAx = fmaf(wA10, vA10.x, aAx); aAy = fmaf(wA10, vA10.y, aAy);
                aAx = fmaf(wA11, vA11.x, aAx); aAy = fmaf(wA11, vA11.y, aAy);
                aBx = fmaf(wB00, vB00.x, aBx); aBy = fmaf(wB00, vB00.y, aBy);
                aBx = fmaf(wB01, vB01.x, aBx); aBy = fmaf(wB01, vB01.y, aBy);
                aBx = fmaf(wB10, vB10.x, aBx); aBy = fmaf(wB10, vB10.y, aBy);
                aBx = fmaf(wB11, vB11.x, aBx); aBy = fmaf(wB11, vB11.y, aBy);
            }
            st[pixA * (X1S / 2) + gA * (GC_ / 2) + k] = make_float2(aAx, aAy);
            st[pixB * (X1S / 2) + gB * (GC_ / 2) + k] = make_float2(aBx, aBy);
        }
    }
    __syncthreads();
    {
        const int pix = t & 15;
        const int cq  = t >> 4;
        #pragma unroll
        for (int i = 0; i < 8; ++i) {
            const int c = cq * 8 + i;
            out[(((size_t)n * C_ + c) * H_ + h) * W_ + w0 + pix] = x1[pix * X1S + c];
        }
    }
}

extern "C" void kernel_launch(void* const* d_in, const int* in_sizes, int n_in,
                              void* d_out, int out_size, void* d_ws, size_t ws_size,
                              hipStream_t stream) {
    const float* inp  = (const float*)d_in[0];
    const float* xin  = (const float*)d_in[1];
    const float* dww  = (const float*)d_in[2];
    const float* dwb  = (const float*)d_in[3];
    const float* lng  = (const float*)d_in[4];
    const float* lnb  = (const float*)d_in[5];
    const float* offw = (const float*)d_in[6];
    const float* offb = (const float*)d_in[7];
    float* outp = (float*)d_out;

    const int blocks = N_ * H_ * (W_ / WT);   // 2048

    if (ws_size >= DESC_BYTES) {
        uint4* desc = (uint4*)d_ws;
        dcn_stage1<<<dim3(blocks), dim3(256), 0, stream>>>(
            inp, dww, dwb, lng, lnb, offw, offb, desc);
        dcn_gather<<<dim3(blocks), dim3(512), 0, stream>>>(xin, desc, outp);
    } else {
        dcn_fused_mono<<<dim3(blocks), dim3(256), 0, stream>>>(
            inp, xin, dww, dwb, lng, lnb, offw, offb, outp);
    }
}

// Round 6
// 97.247 us; speedup vs baseline: 1.0443x; 1.0443x over previous
//
#include <hip/hip_runtime.h>
#include <hip/hip_fp16.h>
#include <math.h>

#define N_  2
#define C_  128
#define H_  128
#define W_  128
#define G_  4
#define GC_ 32
#define P_  9
#define WT  16      // pixels per block (K1/K2, along w)
#define X1S 132     // mono kernel tile stride
#define T1S 133     // K1 x1 tile stride (conflict-free: gcd(5,32)=1)
#define OFS 73      // offs stride (floats)

#define DESC_BYTES ((size_t)N_ * H_ * W_ * G_ * P_ * 16)        // 18.9 MB
#define X1_BYTES   ((size_t)N_ * H_ * W_ * C_ * 4)              // 16.8 MB

union HU { __half h; unsigned short u; };
static __device__ __forceinline__ unsigned int f2h(float f) {
    HU x; x.h = __float2half(f); return (unsigned int)x.u;
}
static __device__ __forceinline__ float h2f(unsigned int v) {
    HU x; x.u = (unsigned short)v; return __half2float(x.h);
}

// ===================== K0: depthwise conv + LN + GELU -> x1 (NHWC, in ws) =====================
// 1024 blocks, 256 thr. Block = 32 px of one row x all 128 ch.
// thread: pq = t&7 (8 quads = 32 px), cg = t>>3 (32 groups of 4 ch).
__global__ __launch_bounds__(256, 4)
void dcn_conv(const float* __restrict__ inp,   // [N,C,H,W]
              const float* __restrict__ dww,   // [3,3,1,C]
              const float* __restrict__ dwb,   // [C]
              const float* __restrict__ lng,   // [C]
              const float* __restrict__ lnb,   // [C]
              float* __restrict__ x1g)         // [N*H*W, C]
{
    __shared__ float red1[32][33];   // [cg][px]
    __shared__ float red2[32][33];
    __shared__ float stat[2][32];    // [mean|rstd][px]

    const int t   = threadIdx.x;
    const int bid = blockIdx.x;
    const int sw  = ((bid & 7) << 7) | (bid >> 3);   // 1024 = 8 XCD x 128
    const int wt  = sw & 3;
    const int h   = (sw >> 2) & (H_ - 1);
    const int n   = sw >> 9;
    const int w0  = wt * 32;
    const int pq  = t & 7;
    const int cg  = t >> 3;
    const int c0  = cg * 4;
    const int bcol = w0 + 4 * pq - 4;
    const int pixbase = (n * H_ + h) * W_ + w0;

    float acc[4][4];                 // [ch][j]
    {
        const float4 bias = *(const float4*)&dwb[c0];
        const float* bp = (const float*)&bias;
        #pragma unroll
        for (int ch = 0; ch < 4; ++ch)
            #pragma unroll
            for (int j = 0; j < 4; ++j) acc[ch][j] = bp[ch];
    }
    const float4 z4 = make_float4(0.f, 0.f, 0.f, 0.f);
    #pragma unroll
    for (int r = 0; r < 3; ++r) {
        const int hr = h - 1 + r;
        const bool rv = (hr >= 0) && (hr < H_);
        const float4 wr0 = *(const float4*)&dww[(r * 3 + 0) * C_ + c0];
        const float4 wr1 = *(const float4*)&dww[(r * 3 + 1) * C_ + c0];
        const float4 wr2 = *(const float4*)&dww[(r * 3 + 2) * C_ + c0];
        #pragma unroll
        for (int ch = 0; ch < 4; ++ch) {
            const float* row = inp + (((size_t)n * C_ + (c0 + ch)) * H_ + hr) * W_;
            const float4 A = (rv && bcol >= 0)   ? *(const float4*)&row[bcol]     : z4;
            const float4 B = rv                  ? *(const float4*)&row[bcol + 4] : z4;
            const float4 Cc= (rv && bcol <= 116) ? *(const float4*)&row[bcol + 8] : z4;
            const float wv0 = A.w, wv1 = B.x, wv2 = B.y, wv3 = B.z, wv4 = B.w, wv5 = Cc.x;
            const float k0 = ((const float*)&wr0)[ch];
            const float k1 = ((const float*)&wr1)[ch];
            const float k2 = ((const float*)&wr2)[ch];
            acc[ch][0] = fmaf(wv0, k0, acc[ch][0]);
            acc[ch][0] = fmaf(wv1, k1, acc[ch][0]);
            acc[ch][0] = fmaf(wv2, k2, acc[ch][0]);
            acc[ch][1] = fmaf(wv1, k0, acc[ch][1]);
            acc[ch][1] = fmaf(wv2, k1, acc[ch][1]);
            acc[ch][1] = fmaf(wv3, k2, acc[ch][1]);
            acc[ch][2] = fmaf(wv2, k0, acc[ch][2]);
            acc[ch][2] = fmaf(wv3, k1, acc[ch][2]);
            acc[ch][2] = fmaf(wv4, k2, acc[ch][2]);
            acc[ch][3] = fmaf(wv3, k0, acc[ch][3]);
            acc[ch][3] = fmaf(wv4, k1, acc[ch][3]);
            acc[ch][3] = fmaf(wv5, k2, acc[ch][3]);
        }
    }
    // per-thread LN partials (4 ch x 4 px -> per-px over own channels)
    #pragma unroll
    for (int j = 0; j < 4; ++j) {
        float s1 = acc[0][j] + acc[1][j] + acc[2][j] + acc[3][j];
        float s2 = acc[0][j] * acc[0][j];
        s2 = fmaf(acc[1][j], acc[1][j], s2);
        s2 = fmaf(acc[2][j], acc[2][j], s2);
        s2 = fmaf(acc[3][j], acc[3][j], s2);
        red1[cg][4 * pq + j] = s1;
        red2[cg][4 * pq + j] = s2;
    }
    __syncthreads();
    if (t < 32) {
        float s1 = 0.f, s2 = 0.f;
        #pragma unroll
        for (int j = 0; j < 32; ++j) { s1 += red1[j][t]; s2 += red2[j][t]; }
        const float mean = s1 * (1.f / 128.f);
        const float var  = s2 * (1.f / 128.f) - mean * mean;
        stat[0][t] = mean;
        stat[1][t] = rsqrtf(var + 1e-6f);
    }
    __syncthreads();
    {
        const float4 lg = *(const float4*)&lng[c0];
        const float4 lb = *(const float4*)&lnb[c0];
        const float* lgp = (const float*)&lg;
        const float* lbp = (const float*)&lb;
        #pragma unroll
        for (int j = 0; j < 4; ++j) {
            const int px = 4 * pq + j;
            const float mean = stat[0][px];
            const float rstd = stat[1][px];
            float4 o;
            float* op = (float*)&o;
            #pragma unroll
            for (int ch = 0; ch < 4; ++ch) {
                float y = (acc[ch][j] - mean) * rstd * lgp[ch] + lbp[ch];
                op[ch] = 0.5f * y * (1.f + erff(y * 0.70710678118654752440f));
            }
            *(float4*)&x1g[(size_t)(pixbase + px) * C_ + c0] = o;
        }
    }
}

// ===================== K1: offset linear + descriptor pack =====================
// 2048 blocks, 256 thr, 16 px each. Reads x1 from ws, writes desc to ws.
#define K1_ARENA (16 * T1S * 4 + 16 * OFS * 4)
__global__ __launch_bounds__(256, 4)
void dcn_offs(const float* __restrict__ x1g,   // [N*H*W, C]
              const float* __restrict__ offw,  // [72,C]
              const float* __restrict__ offb,  // [72]
              uint4* __restrict__ desc)        // [N*H*W, 36]
{
    __shared__ __align__(16) char arena[K1_ARENA];
    float* x1   = (float*)arena;                      // 16 x 133
    float* offs = (float*)(arena + 16 * T1S * 4);     // 16 x 73

    const int t   = threadIdx.x;
    const int bid = blockIdx.x;
    const int sw  = ((bid & 7) << 8) | (bid >> 3);    // 2048 = 8 x 256
    const int wt  = sw & 7;
    const int h   = (sw >> 3) & (H_ - 1);
    const int n   = sw >> 10;
    const int w0  = wt * WT;
    const int pixbase = (n * H_ + h) * W_ + w0;

    // stage x1 tile: 2048 floats, 2 float4/thread
    {
        const int i  = t * 8;
        const int px = i >> 7;
        const int c  = i & 127;
        const float4 a = *(const float4*)&x1g[(size_t)pixbase * C_ + i];
        const float4 b = *(const float4*)&x1g[(size_t)pixbase * C_ + i + 4];
        *(float4*)&x1[px * T1S + c]     = a;
        *(float4*)&x1[px * T1S + c + 4] = b;
    }
    __syncthreads();

    // offset GEMM: thread = (pix, og); og<8 -> 5 outputs, else 4
    {
        const int pix  = t & 15;
        const int s    = t >> 4;
        const bool has5 = (s < 8);
        float acc[5];
        #pragma unroll
        for (int j = 0; j < 4; ++j) acc[j] = offb[s * 4 + j];
        acc[4] = has5 ? offb[64 + s] : 0.f;
        #pragma unroll 2
        for (int cb = 0; cb < C_; cb += 8) {
            const float4 xa = *(const float4*)&x1[pix * T1S + cb];
            const float4 xb = *(const float4*)&x1[pix * T1S + cb + 4];
            #pragma unroll
            for (int j = 0; j < 4; ++j) {
                const int o = s * 4 + j;
                const float4 wa = *(const float4*)&offw[o * C_ + cb];
                const float4 wb = *(const float4*)&offw[o * C_ + cb + 4];
                acc[j] = fmaf(xa.x, wa.x, acc[j]);
                acc[j] = fmaf(xa.y, wa.y, acc[j]);
                acc[j] = fmaf(xa.z, wa.z, acc[j]);
                acc[j] = fmaf(xa.w, wa.w, acc[j]);
                acc[j] = fmaf(xb.x, wb.x, acc[j]);
                acc[j] = fmaf(xb.y, wb.y, acc[j]);
                acc[j] = fmaf(xb.z, wb.z, acc[j]);
                acc[j] = fmaf(xb.w, wb.w, acc[j]);
            }
            if (has5) {
                const int o = 64 + s;
                const float4 wa = *(const float4*)&offw[o * C_ + cb];
                const float4 wb = *(const float4*)&offw[o * C_ + cb + 4];
                acc[4] = fmaf(xa.x, wa.x, acc[4]);
                acc[4] = fmaf(xa.y, wa.y, acc[4]);
                acc[4] = fmaf(xa.z, wa.z, acc[4]);
                acc[4] = fmaf(xa.w, wa.w, acc[4]);
                acc[4] = fmaf(xb.x, wb.x, acc[4]);
                acc[4] = fmaf(xb.y, wb.y, acc[4]);
                acc[4] = fmaf(xb.z, wb.z, acc[4]);
                acc[4] = fmaf(xb.w, wb.w, acc[4]);
            }
        }
        #pragma unroll
        for (int j = 0; j < 4; ++j) offs[pix * OFS + s * 4 + j] = acc[j];
        if (has5) offs[pix * OFS + 64 + s] = acc[4];
    }
    __syncthreads();

    // descriptor pack -> global (coalesced 16B stream)
    {
        for (int tap = t; tap < WT * G_ * P_; tap += 256) {
            const int pg  = tap / 9;
            const int p   = tap - pg * 9;
            const int pix = pg >> 2;
            const int g   = pg & 3;
            const float ox = offs[pix * OFS + g * 18 + 2 * p];
            const float oy = offs[pix * OFS + g * 18 + 2 * p + 1];
            const float fy = (float)(h + (p % 3)) + oy;
            const float fx = (float)(w0 + pix + (p / 3)) + ox;
            const float y0f = floorf(fy);
            const float x0f = floorf(fx);
            const float wy = fy - y0f;
            const float wx = fx - x0f;
            const int y0 = (int)y0f;
            const int x0 = (int)x0f;
            const int yc0 = min(max(y0, 1), H_) - 1;
            const int yc1 = min(max(y0 + 1, 1), H_) - 1;
            const int xc0 = min(max(x0, 1), W_) - 1;
            const int xc1 = min(max(x0 + 1, 1), W_) - 1;
            const float a0 = (1.f - wy) * ((y0 >= 1 && y0 <= H_) ? 1.f : 0.f);
            const float a1 = wy * ((y0 + 1 >= 1 && y0 + 1 <= H_) ? 1.f : 0.f);
            const float b0 = (1.f - wx) * ((x0 >= 1 && x0 <= W_) ? 1.f : 0.f);
            const float b1 = wx * ((x0 + 1 >= 1 && x0 + 1 <= W_) ? 1.f : 0.f);
            const unsigned int i00 = (unsigned int)(yc0 * W_ + xc0);
            const unsigned int i01 = (unsigned int)(yc0 * W_ + xc1);
            const unsigned int i10 = (unsigned int)(yc1 * W_ + xc0);
            const unsigned int i11 = (unsigned int)(yc1 * W_ + xc1);
            desc[(size_t)pixbase * 36 + tap] =
                make_uint4(i00 | (i01 << 16),
                           i10 | (i11 << 16),
                           f2h(a0 * b0) | (f2h(a0 * b1) << 16),
                           f2h(a1 * b0) | (f2h(a1 * b1) << 16));
        }
    }
}

// ===================== K2: pure gather =====================
__global__ __launch_bounds__(512, 4)
void dcn_gather(const float* __restrict__ xin,   // [N,H,W,C]
                const uint4* __restrict__ desc,  // [N*H*W, 36]
                float* __restrict__ out)         // [N,C,H,W]
{
    __shared__ __align__(16) float stage[WT * X1S];

    const int t   = threadIdx.x;
    const int bid = blockIdx.x;
    const int sw  = ((bid & 7) << 8) | (bid >> 3);
    const int wt  = sw & 7;
    const int h   = (sw >> 3) & (H_ - 1);
    const int n   = sw >> 10;
    const int w0  = wt * WT;
    const int pixbase = (n * H_ + h) * W_ + w0;

    {
        const int k   = t & 7;
        const int pl  = t >> 3;
        const int pix = pl >> 2;
        const int g   = pl & 3;
        const uint4* dp = desc + (size_t)(pixbase + pix) * 36 + g * 9;
        const float4* xg = (const float4*)xin + (size_t)n * (H_ * W_ * (C_ / 4)) + g * (GC_ / 4) + k;

        uint4 d[9];
        #pragma unroll
        for (int p = 0; p < P_; ++p) d[p] = dp[p];

        float4 acc = make_float4(0.f, 0.f, 0.f, 0.f);
        #pragma unroll
        for (int p = 0; p < P_; ++p) {
            const float4 v00 = xg[(d[p].x & 0xFFFFu) * 32u];
            const float4 v01 = xg[(d[p].x >> 16) * 32u];
            const float4 v10 = xg[(d[p].y & 0xFFFFu) * 32u];
            const float4 v11 = xg[(d[p].y >> 16) * 32u];
            const float w00 = h2f(d[p].z & 0xFFFFu), w01 = h2f(d[p].z >> 16);
            const float w10 = h2f(d[p].w & 0xFFFFu), w11 = h2f(d[p].w >> 16);
            acc.x = fmaf(w00, v00.x, acc.x);
            acc.y = fmaf(w00, v00.y, acc.y);
            acc.z = fmaf(w00, v00.z, acc.z);
            acc.w = fmaf(w00, v00.w, acc.w);
            acc.x = fmaf(w01, v01.x, acc.x);
            acc.y = fmaf(w01, v01.y, acc.y);
            acc.z = fmaf(w01, v01.z, acc.z);
            acc.w = fmaf(w01, v01.w, acc.w);
            acc.x = fmaf(w10, v10.x, acc.x);
            acc.y = fmaf(w10, v10.y, acc.y);
            acc.z = fmaf(w10, v10.z, acc.z);
            acc.w = fmaf(w10, v10.w, acc.w);
            acc.x = fmaf(w11, v11.x, acc.x);
            acc.y = fmaf(w11, v11.y, acc.y);
            acc.z = fmaf(w11, v11.z, acc.z);
            acc.w = fmaf(w11, v11.w, acc.w);
        }
        *(float4*)&stage[pix * X1S + g * GC_ + k * 4] = acc;
    }
    __syncthreads();
    {
        const int pix = t & 15;
        const int c0  = t >> 4;
        #pragma unroll
        for (int i = 0; i < 4; ++i) {
            const int c = c0 + 32 * i;
            out[(((size_t)n * C_ + c) * H_ + h) * W_ + w0 + pix] = stage[pix * X1S + c];
        }
    }
}

// ===================== middle fallback: R4 stage1 (conv+LN+GELU+GEMM+desc) =====================
#define S1_ARENA (8448 + 4672)
__global__ __launch_bounds__(256, 8)
void dcn_stage1(const float* __restrict__ inp, const float* __restrict__ dww,
                const float* __restrict__ dwb, const float* __restrict__ lng,
                const float* __restrict__ lnb, const float* __restrict__ offw,
                const float* __restrict__ offb, uint4* __restrict__ desc)
{
    __shared__ __align__(16) char arena[S1_ARENA];
    float* x1   = (float*)arena;
    float* offs = (float*)(arena + 8448);
    float* red1 = (float*)(arena + 8448);
    float* red2 = (float*)(arena + 9472);

    const int t   = threadIdx.x;
    const int bid = blockIdx.x;
    const int sw  = ((bid & 7) << 8) | (bid >> 3);
    const int wt  = sw & 7;
    const int h   = (sw >> 3) & (H_ - 1);
    const int n   = sw >> 10;
    const int w0  = wt * WT;
    const int pixbase = (n * H_ + h) * W_ + w0;

    {
        const int w = t & 15;
        const int q = t >> 4;
        float s1 = 0.f, s2 = 0.f;
        const int wcb = w0 + w - 1;
        #pragma unroll
        for (int i = 0; i < 8; ++i) {
            const int c = q * 8 + i;
            float acc = dwb[c];
            #pragma unroll
            for (int r = 0; r < 3; ++r) {
                const int hr = h - 1 + r;
                const bool rv = (hr >= 0) && (hr < H_);
                const float* row = inp + (((size_t)n * C_ + c) * H_ + hr) * W_;
                #pragma unroll
                for (int s = 0; s < 3; ++s) {
                    const int wc = wcb + s;
                    const float v = (rv && wc >= 0 && wc < W_) ? row[wc] : 0.f;
                    acc = fmaf(v, dww[(r * 3 + s) * C_ + c], acc);
                }
            }
            x1[w * X1S + c] = acc;
            s1 += acc;
            s2 = fmaf(acc, acc, s2);
        }
        red1[q * 16 + w] = s1;
        red2[q * 16 + w] = s2;
    }
    __syncthreads();
    {
        const int w = t & 15;
        const int q = t >> 4;
        float s1 = 0.f, s2 = 0.f;
        #pragma unroll
        for (int j = 0; j < 16; ++j) { s1 += red1[j * 16 + w]; s2 += red2[j * 16 + w]; }
        const float mean = s1 * (1.f / 128.f);
        const float var  = s2 * (1.f / 128.f) - mean * mean;
        const float rstd = rsqrtf(var + 1e-6f);
        #pragma unroll
        for (int i = 0; i < 8; ++i) {
            const int c = q * 8 + i;
            float v = x1[w * X1S + c];
            v = (v - mean) * rstd * lng[c] + lnb[c];
            v = 0.5f * v * (1.f + erff(v * 0.70710678118654752440f));
            x1[w * X1S + c] = v;
        }
    }
    __syncthreads();
    {
        const int pix  = t & 15;
        const int s    = t >> 4;
        const bool has5 = (s < 8);
        float acc[5];
        #pragma unroll
        for (int j = 0; j < 4; ++j) acc[j] = offb[s * 4 + j];
        acc[4] = has5 ? offb[64 + s] : 0.f;
        #pragma unroll 1
        for (int cb = 0; cb < C_; cb += 8) {
            const float4 xa = *(const float4*)&x1[pix * X1S + cb];
            const float4 xb = *(const float4*)&x1[pix * X1S + cb + 4];
            #pragma unroll
            for (int j = 0; j < 4; ++j) {
                const int o = s * 4 + j;
                const float4 wa = *(const float4*)&offw[o * C_ + cb];
                const float4 wb = *(const float4*)&offw[o * C_ + cb + 4];
                acc[j] = fmaf(xa.x, wa.x, acc[j]);
                acc[j] = fmaf(xa.y, wa.y, acc[j]);
                acc[j] = fmaf(xa.z, wa.z, acc[j]);
                acc[j] = fmaf(xa.w, wa.w, acc[j]);
                acc[j] = fmaf(xb.x, wb.x, acc[j]);
                acc[j] = fmaf(xb.y, wb.y, acc[j]);
                acc[j] = fmaf(xb.z, wb.z, acc[j]);
                acc[j] = fmaf(xb.w, wb.w, acc[j]);
            }
            if (has5) {
                const int o = 64 + s;
                const float4 wa = *(const float4*)&offw[o * C_ + cb];
                const float4 wb = *(const float4*)&offw[o * C_ + cb + 4];
                acc[4] = fmaf(xa.x, wa.x, acc[4]);
                acc[4] = fmaf(xa.y, wa.y, acc[4]);
                acc[4] = fmaf(xa.z, wa.z, acc[4]);
                acc[4] = fmaf(xa.w, wa.w, acc[4]);
                acc[4] = fmaf(xb.x, wb.x, acc[4]);
                acc[4] = fmaf(xb.y, wb.y, acc[4]);
                acc[4] = fmaf(xb.z, wb.z, acc[4]);
                acc[4] = fmaf(xb.w, wb.w, acc[4]);
            }
        }
        #pragma unroll
        for (int j = 0; j < 4; ++j) offs[pix * OFS + s * 4 + j] = acc[j];
        if (has5) offs[pix * OFS + 64 + s] = acc[4];
    }
    __syncthreads();
    {
        for (int tap = t; tap < WT * G_ * P_; tap += 256) {
            const int pg  = tap / 9;
            const int p   = tap - pg * 9;
            const int pix = pg >> 2;
            const int g   = pg & 3;
            const float ox = offs[pix * OFS + g * 18 + 2 * p];
            const float oy = offs[pix * OFS + g * 18 + 2 * p + 1];
            const float fy = (float)(h + (p % 3)) + oy;
            const float fx = (float)(w0 + pix + (p / 3)) + ox;
            const float y0f = floorf(fy);
            const float x0f = floorf(fx);
            const float wy = fy - y0f;
            const float wx = fx - x0f;
            const int y0 = (int)y0f;
            const int x0 = (int)x0f;
            const int yc0 = min(max(y0, 1), H_) - 1;
            const int yc1 = min(max(y0 + 1, 1), H_) - 1;
            const int xc0 = min(max(x0, 1), W_) - 1;
            const int xc1 = min(max(x0 + 1, 1), W_) - 1;
            const float a0 = (1.f - wy) * ((y0 >= 1 && y0 <= H_) ? 1.f : 0.f);
            const float a1 = wy * ((y0 + 1 >= 1 && y0 + 1 <= H_) ? 1.f : 0.f);
            const float b0 = (1.f - wx) * ((x0 >= 1 && x0 <= W_) ? 1.f : 0.f);
            const float b1 = wx * ((x0 + 1 >= 1 && x0 + 1 <= W_) ? 1.f : 0.f);
            const unsigned int i00 = (unsigned int)(yc0 * W_ + xc0);
            const unsigned int i01 = (unsigned int)(yc0 * W_ + xc1);
            const unsigned int i10 = (unsigned int)(yc1 * W_ + xc0);
            const unsigned int i11 = (unsigned int)(yc1 * W_ + xc1);
            desc[(size_t)pixbase * 36 + tap] =
                make_uint4(i00 | (i01 << 16),
                           i10 | (i11 << 16),
                           f2h(a0 * b0) | (f2h(a0 * b1) << 16),
                           f2h(a1 * b0) | (f2h(a1 * b1) << 16));
        }
    }
}

// ===================== last-resort fallback: monolithic =====================
#define ARENA_BYTES 22336
__global__ __launch_bounds__(256, 6)
void dcn_fused_mono(const float* __restrict__ inp, const float* __restrict__ xin,
                    const float* __restrict__ dww, const float* __restrict__ dwb,
                    const float* __restrict__ lng, const float* __restrict__ lnb,
                    const float* __restrict__ offw, const float* __restrict__ offb,
                    float* __restrict__ out)
{
    __shared__ __align__(16) char arena[ARENA_BYTES];
    float*  x1     = (float*)arena;
    uint4*  desc4  = (uint4*)(arena + 8448);
    float*  red1   = (float*)(arena + 8448);
    float*  red2   = (float*)(arena + 9472);
    float*  offs   = (float*)(arena + 17664);

    const int t   = threadIdx.x;
    const int bid = blockIdx.x;
    const int sw  = ((bid & 7) << 8) | (bid >> 3);
    const int wt  = sw & 7;
    const int h   = (sw >> 3) & (H_ - 1);
    const int n   = sw >> 10;
    const int w0  = wt * WT;

    {
        const int w = t & 15;
        const int q = t >> 4;
        float s1 = 0.f, s2 = 0.f;
        const int wcb = w0 + w - 1;
        #pragma unroll
        for (int i = 0; i < 8; ++i) {
            const int c = q * 8 + i;
            float acc = dwb[c];
            #pragma unroll
            for (int r = 0; r < 3; ++r) {
                const int hr = h - 1 + r;
                const bool rv = (hr >= 0) && (hr < H_);
                const float* row = inp + (((size_t)n * C_ + c) * H_ + hr) * W_;
                #pragma unroll
                for (int s = 0; s < 3; ++s) {
                    const int wc = wcb + s;
                    const float v = (rv && wc >= 0 && wc < W_) ? row[wc] : 0.f;
                    acc = fmaf(v, dww[(r * 3 + s) * C_ + c], acc);
                }
            }
            x1[w * X1S + c] = acc;
            s1 += acc;
            s2 = fmaf(acc, acc, s2);
        }
        red1[q * 16 + w] = s1;
        red2[q * 16 + w] = s2;
    }
    __syncthreads();
    {
        const int w = t & 15;
        const int q = t >> 4;
        float s1 = 0.f, s2 = 0.f;
        #pragma unroll
        for (int j = 0; j < 16; ++j) { s1 += red1[j * 16 + w]; s2 += red2[j * 16 + w]; }
        const float mean = s1 * (1.f / 128.f);
        const float var  = s2 * (1.f / 128.f) - mean * mean;
        const float rstd = rsqrtf(var + 1e-6f);
        #pragma unroll
        for (int i = 0; i < 8; ++i) {
            const int c = q * 8 + i;
            float v = x1[w * X1S + c];
            v = (v - mean) * rstd * lng[c] + lnb[c];
            v = 0.5f * v * (1.f + erff(v * 0.70710678118654752440f));
            x1[w * X1S + c] = v;
        }
    }
    __syncthreads();
    {
        const int pix  = t & 15;
        const int s    = t >> 4;
        const bool has5 = (s < 8);
        float acc[5];
        #pragma unroll
        for (int j = 0; j < 4; ++j) acc[j] = offb[s * 4 + j];
        acc[4] = has5 ? offb[64 + s] : 0.f;
        #pragma unroll 1
        for (int cb = 0; cb < C_; cb += 8) {
            const float4 xa = *(const float4*)&x1[pix * X1S + cb];
            const float4 xb = *(const float4*)&x1[pix * X1S + cb + 4];
            #pragma unroll
            for (int j = 0; j < 4; ++j) {
                const int o = s * 4 + j;
                const float4 wa = *(const float4*)&offw[o * C_ + cb];
                const float4 wb = *(const float4*)&offw[o * C_ + cb + 4];
                acc[j] = fmaf(xa.x, wa.x, acc[j]);
                acc[j] = fmaf(xa.y, wa.y, acc[j]);
                acc[j] = fmaf(xa.z, wa.z, acc[j]);
                acc[j] = fmaf(xa.w, wa.w, acc[j]);
                acc[j] = fmaf(xb.x, wb.x, acc[j]);
                acc[j] = fmaf(xb.y, wb.y, acc[j]);
                acc[j] = fmaf(xb.z, wb.z, acc[j]);
                acc[j] = fmaf(xb.w, wb.w, acc[j]);
            }
            if (has5) {
                const int o = 64 + s;
                const float4 wa = *(const float4*)&offw[o * C_ + cb];
                const float4 wb = *(const float4*)&offw[o * C_ + cb + 4];
                acc[4] = fmaf(xa.x, wa.x, acc[4]);
                acc[4] = fmaf(xa.y, wa.y, acc[4]);
                acc[4] = fmaf(xa.z, wa.z, acc[4]);
                acc[4] = fmaf(xa.w, wa.w, acc[4]);
                acc[4] = fmaf(xb.x, wb.x, acc[4]);
                acc[4] = fmaf(xb.y, wb.y, acc[4]);
                acc[4] = fmaf(xb.z, wb.z, acc[4]);
                acc[4] = fmaf(xb.w, wb.w, acc[4]);
            }
        }
        #pragma unroll
        for (int j = 0; j < 4; ++j) offs[pix * OFS + s * 4 + j] = acc[j];
        if (has5) offs[pix * OFS + 64 + s] = acc[4];
    }
    __syncthreads();
    {
        for (int tap = t; tap < WT * G_ * P_; tap += 256) {
            const int pg  = tap / 9;
            const int p   = tap - pg * 9;
            const int pix = pg >> 2;
            const int g   = pg & 3;
            const float ox = offs[pix * OFS + g * 18 + 2 * p];
            const float oy = offs[pix * OFS + g * 18 + 2 * p + 1];
            const float fy = (float)(h + (p % 3)) + oy;
            const float fx = (float)(w0 + pix + (p / 3)) + ox;
            const float y0f = floorf(fy);
            const float x0f = floorf(fx);
            const float wy = fy - y0f;
            const float wx = fx - x0f;
            const int y0 = (int)y0f;
            const int x0 = (int)x0f;
            const int yc0 = min(max(y0, 1), H_) - 1;
            const int yc1 = min(max(y0 + 1, 1), H_) - 1;
            const int xc0 = min(max(x0, 1), W_) - 1;
            const int xc1 = min(max(x0 + 1, 1), W_) - 1;
            const float a0 = (1.f - wy) * ((y0 >= 1 && y0 <= H_) ? 1.f : 0.f);
            const float a1 = wy * ((y0 + 1 >= 1 && y0 + 1 <= H_) ? 1.f : 0.f);
            const float b0 = (1.f - wx) * ((x0 >= 1 && x0 <= W_) ? 1.f : 0.f);
            const float b1 = wx * ((x0 + 1 >= 1 && x0 + 1 <= W_) ? 1.f : 0.f);
            const unsigned int i00 = (unsigned int)(yc0 * W_ + xc0);
            const unsigned int i01 = (unsigned int)(yc0 * W_ + xc1);
            const unsigned int i10 = (unsigned int)(yc1 * W_ + xc0);
            const unsigned int i11 = (unsigned int)(yc1 * W_ + xc1);
            desc4[tap] = make_uint4(i00 | (i01 << 16),
                                    i10 | (i11 << 16),
                                    f2h(a0 * b0) | (f2h(a0 * b1) << 16),
                                    f2h(a1 * b0) | (f2h(a1 * b1) << 16));
        }
    }
    __syncthreads();
    {
        const int k    = t & 15;
        const int slot = t >> 4;
        const float2* xb2 = (const float2*)xin + (size_t)n * (H_ * W_ * C_ / 2) + k;
        float2* st = (float2*)x1;
        #pragma unroll 1
        for (int it = 0; it < 2; ++it) {
            const int pairA = it * 32 + slot;
            const int pairB = pairA + 16;
            const int pixA = pairA >> 2, gA = pairA & 3;
            const int pixB = pairB >> 2, gB = pairB & 3;
            const float2* xgA = xb2 + gA * (GC_ / 2);
            const float2* xgB = xb2 + gB * (GC_ / 2);
            const uint4* dAp = desc4 + pairA * 9;
            const uint4* dBp = desc4 + pairB * 9;
            float aAx = 0.f, aAy = 0.f, aBx = 0.f, aBy = 0.f;
            #pragma unroll
            for (int p = 0; p < P_; ++p) {
                const uint4 da = dAp[p];
                const uint4 db = dBp[p];
                const float2 vA00 = xgA[(da.x & 0xFFFFu) * 64u];
                const float2 vA01 = xgA[(da.x >> 16) * 64u];
                const float2 vA10 = xgA[(da.y & 0xFFFFu) * 64u];
                const float2 vA11 = xgA[(da.y >> 16) * 64u];
                const float2 vB00 = xgB[(db.x & 0xFFFFu) * 64u];
                const float2 vB01 = xgB[(db.x >> 16) * 64u];
                const float2 vB10 = xgB[(db.y & 0xFFFFu) * 64u];
                const float2 vB11 = xgB[(db.y >> 16) * 64u];
                const float wA00 = h2f(da.z & 0xFFFFu), wA01 = h2f(da.z >> 16);
                const float wA10 = h2f(da.w & 0xFFFFu), wA11 = h2f(da.w >> 16);
                const float wB00 = h2f(db.z & 0xFFFFu), wB01 = h2f(db.z >> 16);
                const float wB10 = h2f(db.w & 0xFFFFu), wB11 = h2f(db.w >> 16);
                aAx = fmaf(wA00, vA00.x, aAx); aAy = fmaf(wA00, vA00.y, aAy);
                aAx = fmaf(wA01, vA01.x, aAx); aAy = fmaf(wA01, vA01.y, aAy);
                aAx = fmaf(wA10, vA10.x, aAx); aAy = fmaf(wA10, vA10.y, aAy);
                aAx = fmaf(wA11, vA11.x, aAx); aAy = fmaf(wA11, vA11.y, aAy);
                aBx = fmaf(wB00, vB00.x, aBx); aBy = fmaf(wB00, vB00.y, aBy);
                aBx = fmaf(wB01, vB01.x, aBx); aBy = fmaf(wB01, vB01.y, aBy);
                aBx = fmaf(wB10, vB10.x, aBx); aBy = fmaf(wB10, vB10.y, aBy);
                aBx = fmaf(wB11, vB11.x, aBx); aBy = fmaf(wB11, vB11.y, aBy);
            }
            st[pixA * (X1S / 2) + gA * (GC_ / 2) + k] = make_float2(aAx, aAy);
            st[pixB * (X1S / 2) + gB * (GC_ / 2) + k] = make_float2(aBx, aBy);
        }
    }
    __syncthreads();
    {
        const int pix = t & 15;
        const int cq  = t >> 4;
        #pragma unroll
        for (int i = 0; i < 8; ++i) {
            const int c = cq * 8 + i;
            out[(((size_t)n * C_ + c) * H_ + h) * W_ + w0 + pix] = x1[pix * X1S + c];
        }
    }
}

extern "C" void kernel_launch(void* const* d_in, const int* in_sizes, int n_in,
                              void* d_out, int out_size, void* d_ws, size_t ws_size,
                              hipStream_t stream) {
    const float* inp  = (const float*)d_in[0];
    const float* xin  = (const float*)d_in[1];
    const float* dww  = (const float*)d_in[2];
    const float* dwb  = (const float*)d_in[3];
    const float* lng  = (const float*)d_in[4];
    const float* lnb  = (const float*)d_in[5];
    const float* offw = (const float*)d_in[6];
    const float* offb = (const float*)d_in[7];
    float* outp = (float*)d_out;

    if (ws_size >= DESC_BYTES + X1_BYTES) {
        uint4* desc = (uint4*)d_ws;
        float* x1g  = (float*)((char*)d_ws + DESC_BYTES);
        dcn_conv<<<dim3(N_ * H_ * (W_ / 32)), dim3(256), 0, stream>>>(
            inp, dww, dwb, lng, lnb, x1g);
        dcn_offs<<<dim3(N_ * H_ * (W_ / WT)), dim3(256), 0, stream>>>(
            x1g, offw, offb, desc);
        dcn_gather<<<dim3(N_ * H_ * (W_ / WT)), dim3(512), 0, stream>>>(
            xin, desc, outp);
    } else if (ws_size >= DESC_BYTES) {
        uint4* desc = (uint4*)d_ws;
        dcn_stage1<<<dim3(N_ * H_ * (W_ / WT)), dim3(256), 0, stream>>>(
            inp, dww, dwb, lng, lnb, offw, offb, desc);
        dcn_gather<<<dim3(N_ * H_ * (W_ / WT)), dim3(512), 0, stream>>>(
            xin, desc, outp);
    } else {
        dcn_fused_mono<<<dim3(N_ * H_ * (W_ / WT)), dim3(256), 0, stream>>>(
            inp, xin, dww, dwb, lng, lnb, offw, offb, outp);
    }
}

// Round 7
// 57.753 us; speedup vs baseline: 1.7585x; 1.6839x over previous
//
#include <hip/hip_runtime.h>
#include <hip/hip_fp16.h>
#include <math.h>

#define N_  2
#define C_  128
#define H_  128
#define W_  128
#define G_  4
#define GC_ 32
#define P_  9
#define WT  16      // pixels per block (K2)
#define X1S 132     // K2 stage / mono tile stride
#define OFS 73      // mono offs stride

#define DESC_BYTES  ((size_t)N_ * H_ * W_ * G_ * P_ * 16)   // 18.9 MB
#define X1BF_BYTES  ((size_t)N_ * H_ * W_ * C_ * 2)         // 8.4 MB

union HU { __half h; unsigned short u; };
static __device__ __forceinline__ unsigned int f2h(float f) {
    HU x; x.h = __float2half(f); return (unsigned int)x.u;
}
static __device__ __forceinline__ float h2f(unsigned int v) {
    HU x; x.u = (unsigned short)v; return __half2float(x.h);
}
static __device__ __forceinline__ unsigned short f2bf(float f) {
    unsigned int u = __float_as_uint(f);
    u += 0x7FFFu + ((u >> 16) & 1u);          // RNE
    return (unsigned short)(u >> 16);
}
static __device__ __forceinline__ float bf2f(unsigned short u) {
    return __uint_as_float(((unsigned int)u) << 16);
}

using bf16x8 = __attribute__((ext_vector_type(8))) short;   // 8 bf16 (4 VGPRs)
using f32x4  = __attribute__((ext_vector_type(4))) float;

// ===================== K0: depthwise conv + LN + GELU -> x1g (bf16 NHWC) =====================
// 1024 blocks x 256 thr. Block = 32 px of one row x all 128 ch.
// LDS: inb bf16[384 segs (c*3+r)][40 cols] = 30720 B; red 2x[8][33] f32; stat[64] f32.
// outt (32x136 bf16) aliases inb after conv.
#define K0_INB_US   (384 * 40)               // ushorts
#define K0_RED1_OFF 30720
#define K0_RED2_OFF (30720 + 1056)
#define K0_STAT_OFF (30720 + 2112)
#define K0_ARENA    (30720 + 2112 + 256)

__global__ __launch_bounds__(256, 4)
void dcn_conv(const float* __restrict__ inp,   // [N,C,H,W]
              const float* __restrict__ dww,   // [3,3,1,C]
              const float* __restrict__ dwb,   // [C]
              const float* __restrict__ lng,   // [C]
              const float* __restrict__ lnb,   // [C]
              unsigned short* __restrict__ x1g)// [N*H*W, C] bf16
{
    __shared__ __align__(16) char arena[K0_ARENA];
    unsigned short* inb  = (unsigned short*)arena;        // [seg][40]
    unsigned short* outt = (unsigned short*)arena;        // [32][136] (alias, post-conv)
    float* red1 = (float*)(arena + K0_RED1_OFF);          // [8][33]
    float* red2 = (float*)(arena + K0_RED2_OFF);
    float* stat = (float*)(arena + K0_STAT_OFF);          // [2][32]

    const int t   = threadIdx.x;
    const int bid = blockIdx.x;
    const int sw  = ((bid & 7) << 7) | (bid >> 3);        // 1024 = 8 XCD x 128
    const int wq  = sw & 3;
    const int h   = (sw >> 2) & (H_ - 1);
    const int n   = sw >> 9;
    const int w0  = wq * 32;
    const int pixbase = (n * H_ + h) * W_ + w0;

    // ---- stage input tile: cols w0-4 .. w0+35 (j 0..39), bf16 ----
    {
        // round A: i = 0..7 (j 0..31)
        #pragma unroll
        for (int rd = 0; rd < 12; ++rd) {
            const int seg = rd * 32 + (t >> 3);
            const int i   = t & 7;
            const int c   = seg / 3;
            const int r   = seg - c * 3;
            const int hr  = h - 1 + r;
            const int col0 = w0 - 4 + 4 * i;
            float4 v = make_float4(0.f, 0.f, 0.f, 0.f);
            if (hr >= 0 && hr < H_ && col0 >= 0 && col0 <= W_ - 4)
                v = *(const float4*)&inp[(((size_t)n * C_ + c) * H_ + hr) * W_ + col0];
            ushort4 pk = make_ushort4(f2bf(v.x), f2bf(v.y), f2bf(v.z), f2bf(v.w));
            *(ushort4*)&inb[seg * 40 + 4 * i] = pk;
        }
        // round B: i = 8..9 (j 32..39)
        #pragma unroll
        for (int rd = 0; rd < 3; ++rd) {
            const int seg = rd * 128 + (t >> 1);
            const int i   = 8 + (t & 1);
            const int c   = seg / 3;
            const int r   = seg - c * 3;
            const int hr  = h - 1 + r;
            const int col0 = w0 - 4 + 4 * i;
            float4 v = make_float4(0.f, 0.f, 0.f, 0.f);
            if (hr >= 0 && hr < H_ && col0 >= 0 && col0 <= W_ - 4)
                v = *(const float4*)&inp[(((size_t)n * C_ + c) * H_ + hr) * W_ + col0];
            ushort4 pk = make_ushort4(f2bf(v.x), f2bf(v.y), f2bf(v.z), f2bf(v.w));
            *(ushort4*)&inb[seg * 40 + 4 * i] = pk;
        }
    }
    __syncthreads();

    // ---- conv: thread = (px = t&31, q = t>>5), 16 ch each ----
    const int px = t & 31;
    const int q  = t >> 5;
    float y[16];
    {
        #pragma unroll
        for (int g4 = 0; g4 < 4; ++g4) {
            const int c0 = q * 16 + g4 * 4;
            float4 wv[9];
            #pragma unroll
            for (int k = 0; k < 9; ++k) wv[k] = *(const float4*)&dww[k * C_ + c0];
            const float4 bias = *(const float4*)&dwb[c0];
            #pragma unroll
            for (int ch = 0; ch < 4; ++ch) {
                const int c = c0 + ch;
                float a = ((const float*)&bias)[ch];
                const unsigned short* rowp = &inb[c * 3 * 40];
                #pragma unroll
                for (int r = 0; r < 3; ++r)
                    #pragma unroll
                    for (int dx = 0; dx < 3; ++dx)
                        a = fmaf(bf2f(rowp[r * 40 + px + dx + 3]),
                                 ((const float*)&wv[r * 3 + dx])[ch], a);
                y[g4 * 4 + ch] = a;
            }
        }
        float s1 = 0.f, s2 = 0.f;
        #pragma unroll
        for (int i = 0; i < 16; ++i) { s1 += y[i]; s2 = fmaf(y[i], y[i], s2); }
        red1[q * 33 + px] = s1;
        red2[q * 33 + px] = s2;
    }
    __syncthreads();

    if (t < 32) {
        float s1 = 0.f, s2 = 0.f;
        #pragma unroll
        for (int j = 0; j < 8; ++j) { s1 += red1[j * 33 + t]; s2 += red2[j * 33 + t]; }
        const float mean = s1 * (1.f / 128.f);
        const float var  = s2 * (1.f / 128.f) - mean * mean;
        stat[t]      = mean;
        stat[32 + t] = rsqrtf(var + 1e-6f);
    }
    __syncthreads();

    // ---- LN + GELU + bf16 pack -> outt (aliases inb; all inb reads done) ----
    {
        const float mean = stat[px];
        const float rstd = stat[32 + px];
        union { unsigned short us[16]; uint4 u4[2]; } o;
        #pragma unroll
        for (int g4 = 0; g4 < 4; ++g4) {
            const int c0 = q * 16 + g4 * 4;
            const float4 lg = *(const float4*)&lng[c0];
            const float4 lb = *(const float4*)&lnb[c0];
            #pragma unroll
            for (int ch = 0; ch < 4; ++ch) {
                float v = (y[g4 * 4 + ch] - mean) * rstd * ((const float*)&lg)[ch]
                          + ((const float*)&lb)[ch];
                v = 0.5f * v * (1.f + erff(v * 0.70710678118654752440f));
                o.us[g4 * 4 + ch] = f2bf(v);
            }
        }
        *(uint4*)&outt[px * 136 + q * 16]     = o.u4[0];
        *(uint4*)&outt[px * 136 + q * 16 + 8] = o.u4[1];
    }
    __syncthreads();

    // ---- coalesced copy out: 32 px x 128 bf16 = 8 KB contiguous ----
    {
        uint4* dst = (uint4*)(x1g + (size_t)pixbase * C_);
        #pragma unroll
        for (int k = 0; k < 2; ++k) {
            const int i  = t + 256 * k;
            const int p2 = i >> 4;
            const int u  = i & 15;
            dst[i] = *(const uint4*)&outt[p2 * 136 + u * 8];
        }
    }
}

// ===================== K1: offset GEMM via MFMA + descriptor pack =====================
// 512 blocks x 256 thr (4 waves). Block = 64 px. LDS:
//   region X: x1t bf16[64][136] (17408 B, padded slot 19456) -- aliased by offs f32[64][76] later
//   region W: offwt bf16[80][136] (21760 B) at 19456
#define K1_X1T_SLOT 19456
#define K1_ARENA    (19456 + 21760)

__global__ __launch_bounds__(256, 2)
void dcn_offs(const unsigned short* __restrict__ x1g,  // [N*H*W, C] bf16
              const float* __restrict__ offw,          // [72,C]
              const float* __restrict__ offb,          // [72]
              uint4* __restrict__ desc)                // [N*H*W, 36]
{
    __shared__ __align__(16) char arena[K1_ARENA];
    unsigned short* x1t   = (unsigned short*)arena;                  // [64][136]
    float*          offs  = (float*)arena;                           // [64][76] (alias)
    unsigned short* offwt = (unsigned short*)(arena + K1_X1T_SLOT);  // [80][136]

    const int t   = threadIdx.x;
    const int bid = blockIdx.x;
    const int sw  = ((bid & 7) << 6) | (bid >> 3);     // 512 = 8 XCD x 64
    const int wh  = sw & 1;
    const int h   = (sw >> 1) & (H_ - 1);
    const int n   = sw >> 8;
    const int w0  = wh * 64;
    const int pixbase = (n * H_ + h) * W_ + w0;

    // ---- stage x1 tile (16 KB) ----
    {
        const uint4* src = (const uint4*)(x1g + (size_t)pixbase * C_);
        #pragma unroll
        for (int k = 0; k < 4; ++k) {
            const int i  = t + 256 * k;      // 1024 uint4
            const int p2 = i >> 4;
            const int u  = i & 15;
            *(uint4*)&x1t[p2 * 136 + u * 8] = src[i];
        }
    }
    // ---- stage offw -> bf16 (72 rows; rows 72-79 garbage, results discarded) ----
    {
        const float4* src = (const float4*)offw;
        #pragma unroll
        for (int k = 0; k < 9; ++k) {
            const int i = t + 256 * k;       // 2304 float4
            const int o = i >> 5;
            const int u = i & 31;
            const float4 v = src[i];
            ushort4 pk = make_ushort4(f2bf(v.x), f2bf(v.y), f2bf(v.z), f2bf(v.w));
            *(ushort4*)&offwt[o * 136 + u * 4] = pk;
        }
    }
    __syncthreads();

    // ---- A-frags + bias ----
    const int lane = t & 63;
    const int wave = t >> 6;
    const int m16  = lane & 15;
    const int kb   = lane >> 4;
    bf16x8 afr[4];
    {
        const int apx = wave * 16 + m16;
        #pragma unroll
        for (int st = 0; st < 4; ++st)
            afr[st] = *(const bf16x8*)&x1t[apx * 136 + st * 32 + kb * 8];
    }
    float bias[5];
    #pragma unroll
    for (int nt = 0; nt < 5; ++nt) {
        const int o = nt * 16 + m16;
        bias[nt] = (o < 72) ? offb[o] : 0.f;
    }
    __syncthreads();   // x1t dead -> offs may be written

    // ---- MFMA: 16(px) x 16(o-tile) x K=128 per wave, 5 o-tiles ----
    #pragma unroll
    for (int nt = 0; nt < 5; ++nt) {
        const int orow = nt * 16 + m16;
        bf16x8 b0 = *(const bf16x8*)&offwt[orow * 136 + 0 * 32 + kb * 8];
        bf16x8 b1 = *(const bf16x8*)&offwt[orow * 136 + 1 * 32 + kb * 8];
        bf16x8 b2 = *(const bf16x8*)&offwt[orow * 136 + 2 * 32 + kb * 8];
        bf16x8 b3 = *(const bf16x8*)&offwt[orow * 136 + 3 * 32 + kb * 8];
        f32x4 acc = {bias[nt], bias[nt], bias[nt], bias[nt]};
        acc = __builtin_amdgcn_mfma_f32_16x16x32_bf16(afr[0], b0, acc, 0, 0, 0);
        acc = __builtin_amdgcn_mfma_f32_16x16x32_bf16(afr[1], b1, acc, 0, 0, 0);
        acc = __builtin_amdgcn_mfma_f32_16x16x32_bf16(afr[2], b2, acc, 0, 0, 0);
        acc = __builtin_amdgcn_mfma_f32_16x16x32_bf16(afr[3], b3, acc, 0, 0, 0);
        // D: col = lane&15 (=o within tile), row = (lane>>4)*4 + reg (=px within wave tile)
        if (orow < 72) {
            #pragma unroll
            for (int reg = 0; reg < 4; ++reg) {
                const int pxl = wave * 16 + kb * 4 + reg;
                offs[pxl * 76 + orow] = acc[reg];
            }
        }
    }
    __syncthreads();

    // ---- descriptor pack: 64 px x 36 taps ----
    #pragma unroll 1
    for (int k = 0; k < 9; ++k) {
        const int tap = t + 256 * k;         // 0..2303
        const int pix = tap / 36;
        const int rem = tap - pix * 36;
        const int g   = rem / 9;
        const int p   = rem - g * 9;
        const float ox = offs[pix * 76 + g * 18 + 2 * p];
        const float oy = offs[pix * 76 + g * 18 + 2 * p + 1];
        const float fy = (float)(h + (p % 3)) + oy;
        const float fx = (float)(w0 + pix + (p / 3)) + ox;
        const float y0f = floorf(fy);
        const float x0f = floorf(fx);
        const float wy = fy - y0f;
        const float wx = fx - x0f;
        const int y0 = (int)y0f;
        const int x0 = (int)x0f;
        const int yc0 = min(max(y0, 1), H_) - 1;
        const int yc1 = min(max(y0 + 1, 1), H_) - 1;
        const int xc0 = min(max(x0, 1), W_) - 1;
        const int xc1 = min(max(x0 + 1, 1), W_) - 1;
        const float a0 = (1.f - wy) * ((y0 >= 1 && y0 <= H_) ? 1.f : 0.f);
        const float a1 = wy * ((y0 + 1 >= 1 && y0 + 1 <= H_) ? 1.f : 0.f);
        const float b0 = (1.f - wx) * ((x0 >= 1 && x0 <= W_) ? 1.f : 0.f);
        const float b1 = wx * ((x0 + 1 >= 1 && x0 + 1 <= W_) ? 1.f : 0.f);
        const unsigned int i00 = (unsigned int)(yc0 * W_ + xc0);
        const unsigned int i01 = (unsigned int)(yc0 * W_ + xc1);
        const unsigned int i10 = (unsigned int)(yc1 * W_ + xc0);
        const unsigned int i11 = (unsigned int)(yc1 * W_ + xc1);
        desc[(size_t)pixbase * 36 + tap] =
            make_uint4(i00 | (i01 << 16),
                       i10 | (i11 << 16),
                       f2h(a0 * b0) | (f2h(a0 * b1) << 16),
                       f2h(a1 * b0) | (f2h(a1 * b1) << 16));
    }
}

// ===================== K2: pure gather =====================
__global__ __launch_bounds__(512, 4)
void dcn_gather(const float* __restrict__ xin,   // [N,H,W,C]
                const uint4* __restrict__ desc,  // [N*H*W, 36]
                float* __restrict__ out)         // [N,C,H,W]
{
    __shared__ __align__(16) float stage[WT * X1S];

    const int t   = threadIdx.x;
    const int bid = blockIdx.x;
    const int sw  = ((bid & 7) << 8) | (bid >> 3);
    const int wt  = sw & 7;
    const int h   = (sw >> 3) & (H_ - 1);
    const int n   = sw >> 10;
    const int w0  = wt * WT;
    const int pixbase = (n * H_ + h) * W_ + w0;

    {
        const int k   = t & 7;
        const int pl  = t >> 3;
        const int pix = pl >> 2;
        const int g   = pl & 3;
        const uint4* dp = desc + (size_t)(pixbase + pix) * 36 + g * 9;
        const float4* xg = (const float4*)xin + (size_t)n * (H_ * W_ * (C_ / 4)) + g * (GC_ / 4) + k;

        uint4 d[9];
        #pragma unroll
        for (int p = 0; p < P_; ++p) d[p] = dp[p];

        float4 acc = make_float4(0.f, 0.f, 0.f, 0.f);
        #pragma unroll
        for (int p = 0; p < P_; ++p) {
            const float4 v00 = xg[(d[p].x & 0xFFFFu) * 32u];
            const float4 v01 = xg[(d[p].x >> 16) * 32u];
            const float4 v10 = xg[(d[p].y & 0xFFFFu) * 32u];
            const float4 v11 = xg[(d[p].y >> 16) * 32u];
            const float w00 = h2f(d[p].z & 0xFFFFu), w01 = h2f(d[p].z >> 16);
            const float w10 = h2f(d[p].w & 0xFFFFu), w11 = h2f(d[p].w >> 16);
            acc.x = fmaf(w00, v00.x, acc.x);
            acc.y = fmaf(w00, v00.y, acc.y);
            acc.z = fmaf(w00, v00.z, acc.z);
            acc.w = fmaf(w00, v00.w, acc.w);
            acc.x = fmaf(w01, v01.x, acc.x);
            acc.y = fmaf(w01, v01.y, acc.y);
            acc.z = fmaf(w01, v01.z, acc.z);
            acc.w = fmaf(w01, v01.w, acc.w);
            acc.x = fmaf(w10, v10.x, acc.x);
            acc.y = fmaf(w10, v10.y, acc.y);
            acc.z = fmaf(w10, v10.z, acc.z);
            acc.w = fmaf(w10, v10.w, acc.w);
            acc.x = fmaf(w11, v11.x, acc.x);
            acc.y = fmaf(w11, v11.y, acc.y);
            acc.z = fmaf(w11, v11.z, acc.z);
            acc.w = fmaf(w11, v11.w, acc.w);
        }
        *(float4*)&stage[pix * X1S + g * GC_ + k * 4] = acc;
    }
    __syncthreads();
    {
        const int pix = t & 15;
        const int c0  = t >> 4;
        #pragma unroll
        for (int i = 0; i < 4; ++i) {
            const int c = c0 + 32 * i;
            out[(((size_t)n * C_ + c) * H_ + h) * W_ + w0 + pix] = stage[pix * X1S + c];
        }
    }
}

// ===================== fallback: monolithic (fp32) =====================
#define ARENA_BYTES 22336
__global__ __launch_bounds__(256, 6)
void dcn_fused_mono(const float* __restrict__ inp, const float* __restrict__ xin,
                    const float* __restrict__ dww, const float* __restrict__ dwb,
                    const float* __restrict__ lng, const float* __restrict__ lnb,
                    const float* __restrict__ offw, const float* __restrict__ offb,
                    float* __restrict__ out)
{
    __shared__ __align__(16) char arena[ARENA_BYTES];
    float*  x1     = (float*)arena;
    uint4*  desc4  = (uint4*)(arena + 8448);
    float*  red1   = (float*)(arena + 8448);
    float*  red2   = (float*)(arena + 9472);
    float*  offs   = (float*)(arena + 17664);

    const int t   = threadIdx.x;
    const int bid = blockIdx.x;
    const int sw  = ((bid & 7) << 8) | (bid >> 3);
    const int wt  = sw & 7;
    const int h   = (sw >> 3) & (H_ - 1);
    const int n   = sw >> 10;
    const int w0  = wt * WT;

    {
        const int w = t & 15;
        const int q = t >> 4;
        float s1 = 0.f, s2 = 0.f;
        const int wcb = w0 + w - 1;
        #pragma unroll
        for (int i = 0; i < 8; ++i) {
            const int c = q * 8 + i;
            float acc = dwb[c];
            #pragma unroll
            for (int r = 0; r < 3; ++r) {
                const int hr = h - 1 + r;
                const bool rv = (hr >= 0) && (hr < H_);
                const float* row = inp + (((size_t)n * C_ + c) * H_ + hr) * W_;
                #pragma unroll
                for (int s = 0; s < 3; ++s) {
                    const int wc = wcb + s;
                    const float v = (rv && wc >= 0 && wc < W_) ? row[wc] : 0.f;
                    acc = fmaf(v, dww[(r * 3 + s) * C_ + c], acc);
                }
            }
            x1[w * X1S + c] = acc;
            s1 += acc;
            s2 = fmaf(acc, acc, s2);
        }
        red1[q * 16 + w] = s1;
        red2[q * 16 + w] = s2;
    }
    __syncthreads();
    {
        const int w = t & 15;
        const int q = t >> 4;
        float s1 = 0.f, s2 = 0.f;
        #pragma unroll
        for (int j = 0; j < 16; ++j) { s1 += red1[j * 16 + w]; s2 += red2[j * 16 + w]; }
        const float mean = s1 * (1.f / 128.f);
        const float var  = s2 * (1.f / 128.f) - mean * mean;
        const float rstd = rsqrtf(var + 1e-6f);
        #pragma unroll
        for (int i = 0; i < 8; ++i) {
            const int c = q * 8 + i;
            float v = x1[w * X1S + c];
            v = (v - mean) * rstd * lng[c] + lnb[c];
            v = 0.5f * v * (1.f + erff(v * 0.70710678118654752440f));
            x1[w * X1S + c] = v;
        }
    }
    __syncthreads();
    {
        const int pix  = t & 15;
        const int s    = t >> 4;
        const bool has5 = (s < 8);
        float acc[5];
        #pragma unroll
        for (int j = 0; j < 4; ++j) acc[j] = offb[s * 4 + j];
        acc[4] = has5 ? offb[64 + s] : 0.f;
        #pragma unroll 1
        for (int cb = 0; cb < C_; cb += 8) {
            const float4 xa = *(const float4*)&x1[pix * X1S + cb];
            const float4 xb = *(const float4*)&x1[pix * X1S + cb + 4];
            #pragma unroll
            for (int j = 0; j < 4; ++j) {
                const int o = s * 4 + j;
                const float4 wa = *(const float4*)&offw[o * C_ + cb];
                const float4 wb = *(const float4*)&offw[o * C_ + cb + 4];
                acc[j] = fmaf(xa.x, wa.x, acc[j]);
                acc[j] = fmaf(xa.y, wa.y, acc[j]);
                acc[j] = fmaf(xa.z, wa.z, acc[j]);
                acc[j] = fmaf(xa.w, wa.w, acc[j]);
                acc[j] = fmaf(xb.x, wb.x, acc[j]);
                acc[j] = fmaf(xb.y, wb.y, acc[j]);
                acc[j] = fmaf(xb.z, wb.z, acc[j]);
                acc[j] = fmaf(xb.w, wb.w, acc[j]);
            }
            if (has5) {
                const int o = 64 + s;
                const float4 wa = *(const float4*)&offw[o * C_ + cb];
                const float4 wb = *(const float4*)&offw[o * C_ + cb + 4];
                acc[4] = fmaf(xa.x, wa.x, acc[4]);
                acc[4] = fmaf(xa.y, wa.y, acc[4]);
                acc[4] = fmaf(xa.z, wa.z, acc[4]);
                acc[4] = fmaf(xa.w, wa.w, acc[4]);
                acc[4] = fmaf(xb.x, wb.x, acc[4]);
                acc[4] = fmaf(xb.y, wb.y, acc[4]);
                acc[4] = fmaf(xb.z, wb.z, acc[4]);
                acc[4] = fmaf(xb.w, wb.w, acc[4]);
            }
        }
        #pragma unroll
        for (int j = 0; j < 4; ++j) offs[pix * OFS + s * 4 + j] = acc[j];
        if (has5) offs[pix * OFS + 64 + s] = acc[4];
    }
    __syncthreads();
    {
        for (int tap = t; tap < WT * G_ * P_; tap += 256) {
            const int pg  = tap / 9;
            const int p   = tap - pg * 9;
            const int pix = pg >> 2;
            const int g   = pg & 3;
            const float ox = offs[pix * OFS + g * 18 + 2 * p];
            const float oy = offs[pix * OFS + g * 18 + 2 * p + 1];
            const float fy = (float)(h + (p % 3)) + oy;
            const float fx = (float)(w0 + pix + (p / 3)) + ox;
            const float y0f = floorf(fy);
            const float x0f = floorf(fx);
            const float wy = fy - y0f;
            const float wx = fx - x0f;
            const int y0 = (int)y0f;
            const int x0 = (int)x0f;
            const int yc0 = min(max(y0, 1), H_) - 1;
            const int yc1 = min(max(y0 + 1, 1), H_) - 1;
            const int xc0 = min(max(x0, 1), W_) - 1;
            const int xc1 = min(max(x0 + 1, 1), W_) - 1;
            const float a0 = (1.f - wy) * ((y0 >= 1 && y0 <= H_) ? 1.f : 0.f);
            const float a1 = wy * ((y0 + 1 >= 1 && y0 + 1 <= H_) ? 1.f : 0.f);
            const float b0 = (1.f - wx) * ((x0 >= 1 && x0 <= W_) ? 1.f : 0.f);
            const float b1 = wx * ((x0 + 1 >= 1 && x0 + 1 <= W_) ? 1.f : 0.f);
            const unsigned int i00 = (unsigned int)(yc0 * W_ + xc0);
            const unsigned int i01 = (unsigned int)(yc0 * W_ + xc1);
            const unsigned int i10 = (unsigned int)(yc1 * W_ + xc0);
            const unsigned int i11 = (unsigned int)(yc1 * W_ + xc1);
            desc4[tap] = make_uint4(i00 | (i01 << 16),
                                    i10 | (i11 << 16),
                                    f2h(a0 * b0) | (f2h(a0 * b1) << 16),
                                    f2h(a1 * b0) | (f2h(a1 * b1) << 16));
        }
    }
    __syncthreads();
    {
        const int k    = t & 15;
        const int slot = t >> 4;
        const float2* xb2 = (const float2*)xin + (size_t)n * (H_ * W_ * C_ / 2) + k;
        float2* st = (float2*)x1;
        #pragma unroll 1
        for (int it = 0; it < 2; ++it) {
            const int pairA = it * 32 + slot;
            const int pairB = pairA + 16;
            const int pixA = pairA >> 2, gA = pairA & 3;
            const int pixB = pairB >> 2, gB = pairB & 3;
            const float2* xgA = xb2 + gA * (GC_ / 2);
            const float2* xgB = xb2 + gB * (GC_ / 2);
            const uint4* dAp = desc4 + pairA * 9;
            const uint4* dBp = desc4 + pairB * 9;
            float aAx = 0.f, aAy = 0.f, aBx = 0.f, aBy = 0.f;
            #pragma unroll
            for (int p = 0; p < P_; ++p) {
                const uint4 da = dAp[p];
                const uint4 db = dBp[p];
                const float2 vA00 = xgA[(da.x & 0xFFFFu) * 64u];
                const float2 vA01 = xgA[(da.x >> 16) * 64u];
                const float2 vA10 = xgA[(da.y & 0xFFFFu) * 64u];
                const float2 vA11 = xgA[(da.y >> 16) * 64u];
                const float2 vB00 = xgB[(db.x & 0xFFFFu) * 64u];
                const float2 vB01 = xgB[(db.x >> 16) * 64u];
                const float2 vB10 = xgB[(db.y & 0xFFFFu) * 64u];
                const float2 vB11 = xgB[(db.y >> 16) * 64u];
                const float wA00 = h2f(da.z & 0xFFFFu), wA01 = h2f(da.z >> 16);
                const float wA10 = h2f(da.w & 0xFFFFu), wA11 = h2f(da.w >> 16);
                const float wB00 = h2f(db.z & 0xFFFFu), wB01 = h2f(db.z >> 16);
                const float wB10 = h2f(db.w & 0xFFFFu), wB11 = h2f(db.w >> 16);
                aAx = fmaf(wA00, vA00.x, aAx); aAy = fmaf(wA00, vA00.y, aAy);
                aAx = fmaf(wA01, vA01.x, aAx); aAy = fmaf(wA01, vA01.y, aAy);
                aAx = fmaf(wA10, vA10.x, aAx); aAy = fmaf(wA10, vA10.y, aAy);
                aAx = fmaf(wA11, vA11.x, aAx); aAy = fmaf(wA11, vA11.y, aAy);
                aBx = fmaf(wB00, vB00.x, aBx); aBy = fmaf(wB00, vB00.y, aBy);
                aBx = fmaf(wB01, vB01.x, aBx); aBy = fmaf(wB01, vB01.y, aBy);
                aBx = fmaf(wB10, vB10.x, aBx); aBy = fmaf(wB10, vB10.y, aBy);
                aBx = fmaf(wB11, vB11.x, aBx); aBy = fmaf(wB11, vB11.y, aBy);
            }
            st[pixA * (X1S / 2) + gA * (GC_ / 2) + k] = make_float2(aAx, aAy);
            st[pixB * (X1S / 2) + gB * (GC_ / 2) + k] = make_float2(aBx, aBy);
        }
    }
    __syncthreads();
    {
        const int pix = t & 15;
        const int cq  = t >> 4;
        #pragma unroll
        for (int i = 0; i < 8; ++i) {
            const int c = cq * 8 + i;
            out[(((size_t)n * C_ + c) * H_ + h) * W_ + w0 + pix] = x1[pix * X1S + c];
        }
    }
}

extern "C" void kernel_launch(void* const* d_in, const int* in_sizes, int n_in,
                              void* d_out, int out_size, void* d_ws, size_t ws_size,
                              hipStream_t stream) {
    const float* inp  = (const float*)d_in[0];
    const float* xin  = (const float*)d_in[1];
    const float* dww  = (const float*)d_in[2];
    const float* dwb  = (const float*)d_in[3];
    const float* lng  = (const float*)d_in[4];
    const float* lnb  = (const float*)d_in[5];
    const float* offw = (const float*)d_in[6];
    const float* offb = (const float*)d_in[7];
    float* outp = (float*)d_out;

    if (ws_size >= DESC_BYTES + X1BF_BYTES) {
        uint4* desc = (uint4*)d_ws;
        unsigned short* x1g = (unsigned short*)((char*)d_ws + DESC_BYTES);
        dcn_conv<<<dim3(N_ * H_ * (W_ / 32)), dim3(256), 0, stream>>>(
            inp, dww, dwb, lng, lnb, x1g);
        dcn_offs<<<dim3(N_ * H_ * (W_ / 64)), dim3(256), 0, stream>>>(
            x1g, offw, offb, desc);
        dcn_gather<<<dim3(N_ * H_ * (W_ / WT)), dim3(512), 0, stream>>>(
            xin, desc, outp);
    } else {
        dcn_fused_mono<<<dim3(N_ * H_ * (W_ / WT)), dim3(256), 0, stream>>>(
            inp, xin, dww, dwb, lng, lnb, offw, offb, outp);
    }
}